// Round 7
// baseline (330.801 us; speedup 1.0000x reference)
//
#include <hip/hip_runtime.h>
#include <stdint.h>
#include <stddef.h>

// Mamba block, B=4 L=2048 D=DI=1024 N=8 K=4 R=64. I/O fp32; GEMMs fp16 MFMA.
// 7 dispatches:
//   prep (wcvt + zero dbl + rmsnorm) -> in_proj -> x_proj (conv fused in A-staging,
//   atomic K-split) -> dt_proj (fp32-A) -> scan1 (conv fused) -> scan2 (conv +
//   prefix-combine fused) -> out_proj
// Scan: NCHUNK=64 chunks of 32, chunk-major state [c][b][d][n].
// ws layout (MiB):
//   [0,16)   xn_h fp16 (rmsnorm out) -> reused as y_h (scan2 out)
//   [16,32)  xbuf_h   [32,48) zbuf_h
//   [64,68)  wih   [68,70) woh   [70,+160K) wxh   [70.5,+128K) wdh
//   [71,73.5) dbl_f fp32 [8192,80]
//   [75,91)  dth fp16 [8192,1024]
//   [91,99)  hF   [99,107) Pb   (fp32, chunk-major)
// WS_NEED = 107 MiB.

typedef unsigned short u16;
typedef unsigned int u32;
typedef _Float16 f16;
typedef __attribute__((ext_vector_type(8))) _Float16 half8;
typedef __attribute__((ext_vector_type(4))) _Float16 half4;
typedef __attribute__((ext_vector_type(4))) float f32x4;

#define LSEQ 2048
#define DMODEL 1024
#define NSTATE 8
#define NCHUNK 64
#define CHUNKL 32
#define NROWS 8192
#define WS_NEED (107ull << 20)

__device__ __forceinline__ void gload_lds16(const void* g, void* l) {
    __builtin_amdgcn_global_load_lds((__attribute__((address_space(1))) void*)g,
                                     (__attribute__((address_space(3))) void*)l,
                                     16, 0, 0);
}

__global__ __launch_bounds__(256) void sentinel_kernel(float* __restrict__ out, int n) {
    int i = blockIdx.x * 256 + threadIdx.x;
    if (i < n) out[i] = 999.0f;
}

// ---- prep: weight fp32->fp16 (4 tensors) + zero dbl_f + rmsnorm ----
#define T0 524288   // in_proj_w /4
#define T1 20480    // x_proj_w /4
#define T2 16384    // dt_proj_w /4
#define T3 262144   // out_proj_w /4
#define WCVT_BLK 3216          // (T0+T1+T2+T3)/256
#define ZERO_BLK 640           // 8192*80*4B / 16B / 256
__global__ __launch_bounds__(256) void prep_kernel(const float* __restrict__ s0,
                                                   const float* __restrict__ s1,
                                                   const float* __restrict__ s2,
                                                   const float* __restrict__ s3,
                                                   f16* __restrict__ d0, f16* __restrict__ d1,
                                                   f16* __restrict__ d2, f16* __restrict__ d3,
                                                   float* __restrict__ dblz,
                                                   const float* __restrict__ X,
                                                   const float* __restrict__ W,
                                                   f16* __restrict__ O) {
    const int bx = blockIdx.x;
    const int tid = threadIdx.x;
    if (bx < WCVT_BLK) {
        int idx = bx * 256 + tid;
        const float* s; f16* d; int i;
        if (idx < T0) { s = s0; d = d0; i = idx; }
        else if (idx < T0 + T1) { s = s1; d = d1; i = idx - T0; }
        else if (idx < T0 + T1 + T2) { s = s2; d = d2; i = idx - T0 - T1; }
        else { s = s3; d = d3; i = idx - T0 - T1 - T2; }
        f32x4 v = *(const f32x4*)(s + (size_t)i * 4);
        half4 o; o[0] = (f16)v[0]; o[1] = (f16)v[1]; o[2] = (f16)v[2]; o[3] = (f16)v[3];
        *(half4*)(d + (size_t)i * 4) = o;
    } else if (bx < WCVT_BLK + ZERO_BLK) {
        int i = (bx - WCVT_BLK) * 256 + tid;
        const f32x4 z4 = {0.f, 0.f, 0.f, 0.f};
        ((f32x4*)dblz)[i] = z4;
    } else {
        const int row = bx - (WCVT_BLK + ZERO_BLK);
        f32x4 u = *(const f32x4*)(X + (size_t)row * DMODEL + tid * 4);
        float ss = u[0]*u[0] + u[1]*u[1] + u[2]*u[2] + u[3]*u[3];
        for (int off = 32; off; off >>= 1) ss += __shfl_down(ss, off, 64);
        __shared__ float red[4];
        if ((tid & 63) == 0) red[tid >> 6] = ss;
        __syncthreads();
        float tot = red[0] + red[1] + red[2] + red[3];
        float scale = rsqrtf(tot * (1.0f / DMODEL) + 1e-5f);
        f32x4 w = *(const f32x4*)(W + tid * 4);
        half4 o;
        o[0] = (f16)(u[0] * scale * w[0]); o[1] = (f16)(u[1] * scale * w[1]);
        o[2] = (f16)(u[2] * scale * w[2]); o[3] = (f16)(u[3] * scale * w[3]);
        *(half4*)(O + (size_t)row * DMODEL + tid * 4) = o;
    }
}

// ---- fp16 GEMM (B^T): C[m,n] = sum_k A[m,k]*Bm[n,k] ------
// tile 128x128, BK=64, 256 thr (4 waves 2x2), mfma_f32_16x16x32_f16.
// AMODE 0: A fp16 via global_load_lds. 1: A fp32, register-converted.
//       2: A fp16 raw pre-conv signal; conv(K=4 along rows)+silu fused in staging.
// EPI 0: split fp16 store. EPI 1: fp32 store. EPI 2: atomicAdd fp32.
// EPI 3: fp16 softplus(acc+fbias).
template <int EPI, int AMODE>
__global__ __launch_bounds__(256) void gemm_f16(const void* __restrict__ Ap, int lda,
                                                const f16* __restrict__ Bm, int ldb,
                                                void* __restrict__ C0, void* __restrict__ C1,
                                                int ldc, int N, int klen,
                                                const float* __restrict__ fbias,
                                                const float* __restrict__ cw,
                                                const float* __restrict__ cb) {
    __shared__ alignas(16) f16 sA[128 * 64];
    __shared__ alignas(16) f16 sB[128 * 64];
    const int tid = threadIdx.x;
    const int wave = tid >> 6, lane = tid & 63;
    const int wm = (wave >> 1) * 64, wn = (wave & 1) * 64;
    const int tm = blockIdx.x, tn = blockIdx.y;
    const int q = lane >> 4, cl = lane & 15;
    const int kbeg = blockIdx.z * klen;

    f32x4 acc[4][4];
    const f32x4 zero4 = {0.f, 0.f, 0.f, 0.f};
#pragma unroll
    for (int t = 0; t < 4; t++)
#pragma unroll
        for (int u = 0; u < 4; u++) acc[t][u] = zero4;

    int rS[4], gkS[4];
#pragma unroll
    for (int j = 0; j < 4; j++) {
        int c = wave * 256 + j * 64 + lane;
        rS[j] = c >> 3;
        gkS[j] = (c & 7) ^ (rS[j] & 7);
    }

    for (int k0 = kbeg; k0 < kbeg + klen; k0 += 64) {
        __syncthreads();
#pragma unroll
        for (int j = 0; j < 4; j++) {
            int ldsoff = (wave * 256 + j * 64) * 8;
            if (AMODE == 0) {
                int ga = tm * 128 + rS[j];
                gload_lds16((const f16*)Ap + (size_t)ga * lda + k0 + gkS[j] * 8, sA + ldsoff);
            }
            int gb = tn * 128 + rS[j];
            if (gb >= N) gb = N - 1;
            gload_lds16(Bm + (size_t)gb * ldb + k0 + gkS[j] * 8, sB + ldsoff);
        }
        __syncthreads();

        half8 af[4][2], bf[4][2];
        if (AMODE == 2) {
            // fused depthwise conv(K=4 along rows) + silu, channels = k dim
#pragma unroll
            for (int s = 0; s < 2; s++) {
                int kch = k0 + (s * 4 + q) * 8;     // channel base for this frag
                float cwv[4][8], cbv[8];
#pragma unroll
                for (int e = 0; e < 8; e++) {
                    f32x4 c4 = *(const f32x4*)(cw + (size_t)(kch + e) * 4);
                    cwv[0][e] = c4[0]; cwv[1][e] = c4[1]; cwv[2][e] = c4[2]; cwv[3][e] = c4[3];
                    cbv[e] = cb[kch + e];
                }
#pragma unroll
                for (int t = 0; t < 4; t++) {
                    int m = tm * 128 + wm + t * 16 + cl;
                    int l = m & (LSEQ - 1);
                    half8 xr[4];
#pragma unroll
                    for (int jj = 0; jj < 4; jj++) {
                        if (l - 3 + jj >= 0)
                            xr[jj] = *(const half8*)((const f16*)Ap + (size_t)(m - 3 + jj) * lda + kch);
                        else {
                            half8 zz = {0, 0, 0, 0, 0, 0, 0, 0};
                            xr[jj] = zz;
                        }
                    }
                    half8 a;
#pragma unroll
                    for (int e = 0; e < 8; e++) {
                        float v = cbv[e] + cwv[0][e] * (float)xr[0][e] + cwv[1][e] * (float)xr[1][e]
                                + cwv[2][e] * (float)xr[2][e] + cwv[3][e] * (float)xr[3][e];
                        v = v / (1.f + __expf(-v));
                        a[e] = (f16)v;
                    }
                    af[t][s] = a;
                }
            }
        }
#pragma unroll
        for (int t = 0; t < 4; t++)
#pragma unroll
            for (int s = 0; s < 2; s++) {
                int m = wm + t * 16 + cl;
                int kc = s * 4 + q;
                if (AMODE == 1) {
                    const float* pa = (const float*)Ap + (size_t)(tm * 128 + m) * lda + k0 + kc * 8;
                    f32x4 v0 = *(const f32x4*)pa, v1 = *(const f32x4*)(pa + 4);
                    half8 a;
                    a[0] = (f16)v0[0]; a[1] = (f16)v0[1]; a[2] = (f16)v0[2]; a[3] = (f16)v0[3];
                    a[4] = (f16)v1[0]; a[5] = (f16)v1[1]; a[6] = (f16)v1[2]; a[7] = (f16)v1[3];
                    af[t][s] = a;
                } else if (AMODE == 0) {
                    af[t][s] = *(const half8*)(sA + m * 64 + ((kc ^ (m & 7)) << 3));
                }
                int n = wn + t * 16 + cl;
                bf[t][s] = *(const half8*)(sB + n * 64 + ((kc ^ (n & 7)) << 3));
            }
#pragma unroll
        for (int t = 0; t < 4; t++)
#pragma unroll
            for (int u = 0; u < 4; u++) {
                acc[t][u] = __builtin_amdgcn_mfma_f32_16x16x32_f16(af[t][0], bf[u][0], acc[t][u], 0, 0, 0);
                acc[t][u] = __builtin_amdgcn_mfma_f32_16x16x32_f16(af[t][1], bf[u][1], acc[t][u], 0, 0, 0);
            }
    }

    const int rowbase = tm * 128 + wm + q * 4;
    const int colbase = tn * 128 + wn + cl;
#pragma unroll
    for (int t = 0; t < 4; t++)
#pragma unroll
        for (int r = 0; r < 4; r++) {
            size_t rb_ = (size_t)(rowbase + t * 16 + r) * ldc;
            size_t rb1 = (size_t)(rowbase + t * 16 + r) * 1024;
#pragma unroll
            for (int u = 0; u < 4; u++) {
                int gcol = colbase + u * 16;
                float v = acc[t][u][r];
                if (EPI == 0) {
                    if (gcol < 1024) ((f16*)C0)[rb1 + gcol] = (f16)v;
                    else             ((f16*)C1)[rb1 + gcol - 1024] = (f16)v;
                } else if (EPI == 1) {
                    if (gcol < N) ((float*)C0)[rb_ + gcol] = v;
                } else if (EPI == 2) {
                    if (gcol < N) atomicAdd((float*)C0 + rb_ + gcol, v);
                } else {
                    if (gcol < N) {
                        float sv = v + fbias[gcol];
                        sv = (sv > 15.f) ? sv : log1pf(__expf(sv));
                        ((f16*)C0)[rb_ + gcol] = (f16)sv;
                    }
                }
            }
        }
}

// ---------------- selective scan: 64 chunks of 32, chunk-major state --------
// conv(K=4)+silu fused via sliding window (x from raw xbuf).
// state layout: hF/Pb [c][b][d][n] -> offset ((c*4+b)*1024+d)*8+n
__global__ __launch_bounds__(256) void scan1_kernel(const f16* __restrict__ dt,
                                                    const f16* __restrict__ xb,
                                                    const float* __restrict__ dbl,
                                                    const float* __restrict__ A_log,
                                                    const float* __restrict__ cw,
                                                    const float* __restrict__ cb,
                                                    float* __restrict__ hF,
                                                    float* __restrict__ Pb) {
    const int d = blockIdx.x * 256 + threadIdx.x;
    const int c = blockIdx.y;
    const int b = blockIdx.z;
    __shared__ float sB[CHUNKL * NSTATE];   // 256 floats
    sB[threadIdx.x] = dbl[(size_t)(b * LSEQ + c * CHUNKL + (threadIdx.x >> 3)) * 80 + 64 + (threadIdx.x & 7)];
    __syncthreads();
    f32x4 al0 = *(const f32x4*)(A_log + d * 8);
    f32x4 al1 = *(const f32x4*)(A_log + d * 8 + 4);
    float Aa[NSTATE];
#pragma unroll
    for (int n = 0; n < 4; n++) { Aa[n] = -__expf(al0[n]); Aa[n + 4] = -__expf(al1[n]); }
    f32x4 cwv = *(const f32x4*)(cw + d * 4);
    const float cbv = cb[d];
    float h[NSTATE], P[NSTATE];
#pragma unroll
    for (int n = 0; n < NSTATE; n++) { h[n] = 0.f; P[n] = 1.f; }
    const size_t rowoff = (size_t)(b * LSEQ + c * CHUNKL) * 1024 + d;
    const f16* pdt = dt + rowoff;
    const f16* px = xb + rowoff;
    float xm3 = 0.f, xm2 = 0.f, xm1 = 0.f;
    if (c > 0) {
        xm3 = (float)px[-3 * 1024]; xm2 = (float)px[-2 * 1024]; xm1 = (float)px[-1 * 1024];
    }
    for (int lb = 0; lb < CHUNKL; lb += 8) {
        float vdt[8], vx[8];
#pragma unroll
        for (int j = 0; j < 8; j++) {       // batch loads: one stall per 8 steps
            vdt[j] = (float)pdt[(size_t)(lb + j) * 1024];
            vx[j] = (float)px[(size_t)(lb + j) * 1024];
        }
#pragma unroll
        for (int j = 0; j < 8; j++) {
            float cv = cbv + cwv[0] * xm3 + cwv[1] * xm2 + cwv[2] * xm1 + cwv[3] * vx[j];
            xm3 = xm2; xm2 = xm1; xm1 = vx[j];
            float xv = cv / (1.f + __expf(-cv));
            float dtx = vdt[j] * xv;
#pragma unroll
            for (int n = 0; n < NSTATE; n++) {
                float e = __expf(Aa[n] * vdt[j]);
                h[n] = e * h[n] + dtx * sB[(lb + j) * 8 + n];
                P[n] *= e;
            }
        }
    }
    size_t base = ((size_t)(c * 4 + b) * 1024 + d) * 8;
    f32x4 o;
    o[0]=h[0]; o[1]=h[1]; o[2]=h[2]; o[3]=h[3]; *(f32x4*)(hF + base) = o;
    o[0]=h[4]; o[1]=h[5]; o[2]=h[6]; o[3]=h[7]; *(f32x4*)(hF + base + 4) = o;
    o[0]=P[0]; o[1]=P[1]; o[2]=P[2]; o[3]=P[3]; *(f32x4*)(Pb + base) = o;
    o[0]=P[4]; o[1]=P[5]; o[2]=P[6]; o[3]=P[7]; *(f32x4*)(Pb + base + 4) = o;
}

// pass 2: inline coalesced prefix walk + conv-fused replay + D-skip + silu(z)
__global__ __launch_bounds__(256) void scan2_kernel(const f16* __restrict__ dt,
                                                    const f16* __restrict__ xb,
                                                    const float* __restrict__ dbl,
                                                    const float* __restrict__ A_log,
                                                    const float* __restrict__ hF,
                                                    const float* __restrict__ Pb,
                                                    const float* __restrict__ cw,
                                                    const float* __restrict__ cb,
                                                    const f16* __restrict__ z,
                                                    const float* __restrict__ Dsk,
                                                    f16* __restrict__ yout) {
    const int d = blockIdx.x * 256 + threadIdx.x;
    const int c = blockIdx.y;
    const int b = blockIdx.z;
    __shared__ float sB[CHUNKL * NSTATE];
    __shared__ float sC[CHUNKL * NSTATE];
    {
        size_t rb = (size_t)(b * LSEQ + c * CHUNKL + (threadIdx.x >> 3)) * 80;
        sB[threadIdx.x] = dbl[rb + 64 + (threadIdx.x & 7)];
        sC[threadIdx.x] = dbl[rb + 72 + (threadIdx.x & 7)];
    }
    __syncthreads();
    f32x4 al0 = *(const f32x4*)(A_log + d * 8);
    f32x4 al1 = *(const f32x4*)(A_log + d * 8 + 4);
    float Aa[NSTATE];
#pragma unroll
    for (int n = 0; n < 4; n++) { Aa[n] = -__expf(al0[n]); Aa[n + 4] = -__expf(al1[n]); }
    // coalesced prefix walk: h = exclusive prefix state entering chunk c
    float h[NSTATE];
#pragma unroll
    for (int n = 0; n < NSTATE; n++) h[n] = 0.f;
    {
        size_t off = ((size_t)b * 1024 + d) * 8;
#pragma unroll 4
        for (int cc = 0; cc < c; cc++) {
            size_t base = (size_t)cc * 32768 + off;
            f32x4 p0 = *(const f32x4*)(Pb + base), p1 = *(const f32x4*)(Pb + base + 4);
            f32x4 g0 = *(const f32x4*)(hF + base), g1 = *(const f32x4*)(hF + base + 4);
#pragma unroll
            for (int n = 0; n < 4; n++) {
                h[n] = fmaf(p0[n], h[n], g0[n]);
                h[n + 4] = fmaf(p1[n], h[n + 4], g1[n]);
            }
        }
    }
    f32x4 cwv = *(const f32x4*)(cw + d * 4);
    const float cbv = cb[d];
    const float dval = Dsk[d];
    const size_t rowoff = (size_t)(b * LSEQ + c * CHUNKL) * 1024 + d;
    const f16* pdt = dt + rowoff;
    const f16* px = xb + rowoff;
    const f16* pz = z + rowoff;
    f16* py = yout + rowoff;
    float xm3 = 0.f, xm2 = 0.f, xm1 = 0.f;
    if (c > 0) {
        xm3 = (float)px[-3 * 1024]; xm2 = (float)px[-2 * 1024]; xm1 = (float)px[-1 * 1024];
    }
    for (int lb = 0; lb < CHUNKL; lb += 8) {
        float vdt[8], vx[8], vz[8];
#pragma unroll
        for (int j = 0; j < 8; j++) {
            vdt[j] = (float)pdt[(size_t)(lb + j) * 1024];
            vx[j] = (float)px[(size_t)(lb + j) * 1024];
            vz[j] = (float)pz[(size_t)(lb + j) * 1024];
        }
#pragma unroll
        for (int j = 0; j < 8; j++) {
            float cv = cbv + cwv[0] * xm3 + cwv[1] * xm2 + cwv[2] * xm1 + cwv[3] * vx[j];
            xm3 = xm2; xm2 = xm1; xm1 = vx[j];
            float xv = cv / (1.f + __expf(-cv));
            float dtx = vdt[j] * xv;
            float y = 0.f;
#pragma unroll
            for (int n = 0; n < NSTATE; n++) {
                float e = __expf(Aa[n] * vdt[j]);
                h[n] = e * h[n] + dtx * sB[(lb + j) * 8 + n];
                y += h[n] * sC[(lb + j) * 8 + n];
            }
            y += dval * xv;
            y *= vz[j] / (1.f + __expf(-vz[j]));
            py[(size_t)(lb + j) * 1024] = (f16)y;
        }
    }
}

extern "C" void kernel_launch(void* const* d_in, const int* in_sizes, int n_in,
                              void* d_out, int out_size, void* d_ws, size_t ws_size,
                              hipStream_t stream) {
    (void)in_sizes; (void)n_in;
    const float* hidden    = (const float*)d_in[0];
    const float* norm_w    = (const float*)d_in[1];
    const float* in_proj_w = (const float*)d_in[2];
    const float* conv_w    = (const float*)d_in[3];
    const float* conv_b    = (const float*)d_in[4];
    const float* x_proj_w  = (const float*)d_in[5];
    const float* dt_proj_w = (const float*)d_in[6];
    const float* dt_proj_b = (const float*)d_in[7];
    const float* A_log     = (const float*)d_in[8];
    const float* D_skip    = (const float*)d_in[9];
    const float* out_proj_w= (const float*)d_in[10];
    float* out = (float*)d_out;

    if (ws_size < WS_NEED) {
        sentinel_kernel<<<dim3((out_size + 255) / 256), 256, 0, stream>>>(out, out_size);
        return;
    }

    char* ws = (char*)d_ws;
    f16*   xn_h  = (f16*)(ws);                         // [0,16) -> y_h later
    f16*   xbuf_h= (f16*)(ws + (16ull << 20));         // [16,32)
    f16*   zbuf_h= (f16*)(ws + (32ull << 20));         // [32,48)
    f16*   wih   = (f16*)(ws + (64ull << 20));         // [64,68)
    f16*   woh   = (f16*)(ws + (68ull << 20));         // [68,70)
    f16*   wxh   = (f16*)(ws + (70ull << 20));         // 160 KB
    f16*   wdh   = (f16*)(ws + (70ull << 20) + (512ull << 10));  // 128 KB
    float* dbl_f = (float*)(ws + (71ull << 20));       // 2.5 MB
    f16*   dth   = (f16*)(ws + (75ull << 20));         // [75,91)
    float* hF    = (float*)(ws + (91ull << 20));       // 8 MB
    float* Pb    = (float*)(ws + (99ull << 20));       // 8 MB
    f16*   y_h   = xn_h;

    prep_kernel<<<dim3(WCVT_BLK + ZERO_BLK + NROWS), 256, 0, stream>>>(
        in_proj_w, x_proj_w, dt_proj_w, out_proj_w, wih, wxh, wdh, woh,
        dbl_f, hidden, norm_w, xn_h);
    gemm_f16<0, 0><<<dim3(64, 16), 256, 0, stream>>>(xn_h, 1024, wih, 1024,
                                                     xbuf_h, zbuf_h, 1024, 2048, 1024,
                                                     nullptr, nullptr, nullptr);
    // x_proj: conv+silu fused into A-staging, K-split x4 atomic accumulate
    gemm_f16<2, 2><<<dim3(64, 1, 4), 256, 0, stream>>>(xbuf_h, 1024, wxh, 1024,
                                                       dbl_f, nullptr, 80, 80, 256,
                                                       nullptr, conv_w, conv_b);
    // dt_proj: fp32 A (dbl_f cols 0..63), K=64, softplus epilogue -> dth fp16
    gemm_f16<3, 1><<<dim3(64, 8), 256, 0, stream>>>(dbl_f, 80, wdh, 64,
                                                    dth, nullptr, 1024, 1024, 64,
                                                    dt_proj_b, nullptr, nullptr);
    scan1_kernel<<<dim3(4, NCHUNK, 4), 256, 0, stream>>>(dth, xbuf_h, dbl_f, A_log,
                                                         conv_w, conv_b, hF, Pb);
    scan2_kernel<<<dim3(4, NCHUNK, 4), 256, 0, stream>>>(dth, xbuf_h, dbl_f, A_log, hF, Pb,
                                                         conv_w, conv_b, zbuf_h, D_skip, y_h);
    gemm_f16<1, 0><<<dim3(64, 8), 256, 0, stream>>>(y_h, 1024, woh, 1024,
                                                    out, nullptr, 1024, 1024, 1024,
                                                    nullptr, nullptr, nullptr);
}

// Round 8
// 295.908 us; speedup vs baseline: 1.1179x; 1.1179x over previous
//
#include <hip/hip_runtime.h>
#include <stdint.h>
#include <stddef.h>

// Mamba block, B=4 L=2048 D=DI=1024 N=8 K=4 R=64. I/O fp32; GEMMs fp16 MFMA,
// m97-style global_load_lds staging. 9 dispatches (round-6 proven structure):
//   prep (wcvt + zero dbl + rmsnorm) -> in_proj -> conv -> x_proj(atomic K-split)
//   -> dt_proj (fp32-A) -> scan1 -> combine -> scan2 -> out_proj
// Scan: NCHUNK=64 chunks of 32, chunk-major state [c][b][d][n],
// double-buffered (software-pipelined) load batches in scan1/scan2.
// ws layout (MiB):
//   [0,16)   xn_h fp16 (rmsnorm out) -> reused as y_h (scan2 out)
//   [16,32)  xbuf_h   [32,48) zbuf_h   [48,64) xc_h
//   [64,68)  wih   [68,70) woh   [70,+160K) wxh   [70.5,+128K) wdh
//   [71,73.5) dbl_f fp32 [8192,80]
//   [75,91)  dth fp16 [8192,1024]
//   [91,99)  hF   [99,107) Pb   [107,115) h0   (fp32, chunk-major)
// WS_NEED = 115 MiB.

typedef unsigned short u16;
typedef unsigned int u32;
typedef _Float16 f16;
typedef __attribute__((ext_vector_type(8))) _Float16 half8;
typedef __attribute__((ext_vector_type(4))) _Float16 half4;
typedef __attribute__((ext_vector_type(4))) float f32x4;

#define LSEQ 2048
#define DMODEL 1024
#define NSTATE 8
#define NCHUNK 64
#define CHUNKL 32
#define NROWS 8192
#define WS_NEED (115ull << 20)

__device__ __forceinline__ void gload_lds16(const void* g, void* l) {
    __builtin_amdgcn_global_load_lds((__attribute__((address_space(1))) void*)g,
                                     (__attribute__((address_space(3))) void*)l,
                                     16, 0, 0);
}

__global__ __launch_bounds__(256) void sentinel_kernel(float* __restrict__ out, int n) {
    int i = blockIdx.x * 256 + threadIdx.x;
    if (i < n) out[i] = 999.0f;
}

// ---- prep: weight fp32->fp16 (4 tensors) + zero dbl_f + rmsnorm ----
#define T0 524288   // in_proj_w /4
#define T1 20480    // x_proj_w /4
#define T2 16384    // dt_proj_w /4
#define T3 262144   // out_proj_w /4
#define WCVT_BLK 3216          // (T0+T1+T2+T3)/256
#define ZERO_BLK 640           // 8192*80*4B / 16B / 256
__global__ __launch_bounds__(256) void prep_kernel(const float* __restrict__ s0,
                                                   const float* __restrict__ s1,
                                                   const float* __restrict__ s2,
                                                   const float* __restrict__ s3,
                                                   f16* __restrict__ d0, f16* __restrict__ d1,
                                                   f16* __restrict__ d2, f16* __restrict__ d3,
                                                   float* __restrict__ dblz,
                                                   const float* __restrict__ X,
                                                   const float* __restrict__ W,
                                                   f16* __restrict__ O) {
    const int bx = blockIdx.x;
    const int tid = threadIdx.x;
    if (bx < WCVT_BLK) {
        int idx = bx * 256 + tid;
        const float* s; f16* d; int i;
        if (idx < T0) { s = s0; d = d0; i = idx; }
        else if (idx < T0 + T1) { s = s1; d = d1; i = idx - T0; }
        else if (idx < T0 + T1 + T2) { s = s2; d = d2; i = idx - T0 - T1; }
        else { s = s3; d = d3; i = idx - T0 - T1 - T2; }
        f32x4 v = *(const f32x4*)(s + (size_t)i * 4);
        half4 o; o[0] = (f16)v[0]; o[1] = (f16)v[1]; o[2] = (f16)v[2]; o[3] = (f16)v[3];
        *(half4*)(d + (size_t)i * 4) = o;
    } else if (bx < WCVT_BLK + ZERO_BLK) {
        int i = (bx - WCVT_BLK) * 256 + tid;
        const f32x4 z4 = {0.f, 0.f, 0.f, 0.f};
        ((f32x4*)dblz)[i] = z4;
    } else {
        const int row = bx - (WCVT_BLK + ZERO_BLK);
        f32x4 u = *(const f32x4*)(X + (size_t)row * DMODEL + tid * 4);
        float ss = u[0]*u[0] + u[1]*u[1] + u[2]*u[2] + u[3]*u[3];
        for (int off = 32; off; off >>= 1) ss += __shfl_down(ss, off, 64);
        __shared__ float red[4];
        if ((tid & 63) == 0) red[tid >> 6] = ss;
        __syncthreads();
        float tot = red[0] + red[1] + red[2] + red[3];
        float scale = rsqrtf(tot * (1.0f / DMODEL) + 1e-5f);
        f32x4 w = *(const f32x4*)(W + tid * 4);
        half4 o;
        o[0] = (f16)(u[0] * scale * w[0]); o[1] = (f16)(u[1] * scale * w[1]);
        o[2] = (f16)(u[2] * scale * w[2]); o[3] = (f16)(u[3] * scale * w[3]);
        *(half4*)(O + (size_t)row * DMODEL + tid * 4) = o;
    }
}

// ---- fp16 GEMM (B^T): C[m,n] = sum_k A[m,k]*Bm[n,k] ------
// tile 128x128, BK=64, 256 thr (4 waves 2x2), mfma_f32_16x16x32_f16.
// AF32: A fp32, fragments converted in-register. EPI 0: split fp16 store.
// EPI 1: fp32 store. EPI 2: atomicAdd fp32. EPI 3: fp16 softplus(acc+fbias).
template <int EPI, int AF32>
__global__ __launch_bounds__(256) void gemm_f16(const void* __restrict__ Ap, int lda,
                                                const f16* __restrict__ Bm, int ldb,
                                                void* __restrict__ C0, void* __restrict__ C1,
                                                int ldc, int N, int klen,
                                                const float* __restrict__ fbias) {
    __shared__ alignas(16) f16 sA[128 * 64];
    __shared__ alignas(16) f16 sB[128 * 64];
    const int tid = threadIdx.x;
    const int wave = tid >> 6, lane = tid & 63;
    const int wm = (wave >> 1) * 64, wn = (wave & 1) * 64;
    const int tm = blockIdx.x, tn = blockIdx.y;
    const int q = lane >> 4, cl = lane & 15;
    const int kbeg = blockIdx.z * klen;

    f32x4 acc[4][4];
    const f32x4 zero4 = {0.f, 0.f, 0.f, 0.f};
#pragma unroll
    for (int t = 0; t < 4; t++)
#pragma unroll
        for (int u = 0; u < 4; u++) acc[t][u] = zero4;

    int rS[4], gkS[4];
#pragma unroll
    for (int j = 0; j < 4; j++) {
        int c = wave * 256 + j * 64 + lane;
        rS[j] = c >> 3;
        gkS[j] = (c & 7) ^ (rS[j] & 7);
    }

    for (int k0 = kbeg; k0 < kbeg + klen; k0 += 64) {
        __syncthreads();
#pragma unroll
        for (int j = 0; j < 4; j++) {
            int ldsoff = (wave * 256 + j * 64) * 8;
            if (!AF32) {
                int ga = tm * 128 + rS[j];
                gload_lds16((const f16*)Ap + (size_t)ga * lda + k0 + gkS[j] * 8, sA + ldsoff);
            }
            int gb = tn * 128 + rS[j];
            if (gb >= N) gb = N - 1;
            gload_lds16(Bm + (size_t)gb * ldb + k0 + gkS[j] * 8, sB + ldsoff);
        }
        __syncthreads();

        half8 af[4][2], bf[4][2];
#pragma unroll
        for (int t = 0; t < 4; t++)
#pragma unroll
            for (int s = 0; s < 2; s++) {
                int m = wm + t * 16 + cl;
                int kc = s * 4 + q;
                if (AF32) {
                    const float* pa = (const float*)Ap + (size_t)(tm * 128 + m) * lda + k0 + kc * 8;
                    f32x4 v0 = *(const f32x4*)pa, v1 = *(const f32x4*)(pa + 4);
                    half8 a;
                    a[0] = (f16)v0[0]; a[1] = (f16)v0[1]; a[2] = (f16)v0[2]; a[3] = (f16)v0[3];
                    a[4] = (f16)v1[0]; a[5] = (f16)v1[1]; a[6] = (f16)v1[2]; a[7] = (f16)v1[3];
                    af[t][s] = a;
                } else {
                    af[t][s] = *(const half8*)(sA + m * 64 + ((kc ^ (m & 7)) << 3));
                }
                int n = wn + t * 16 + cl;
                bf[t][s] = *(const half8*)(sB + n * 64 + ((kc ^ (n & 7)) << 3));
            }
#pragma unroll
        for (int t = 0; t < 4; t++)
#pragma unroll
            for (int u = 0; u < 4; u++) {
                acc[t][u] = __builtin_amdgcn_mfma_f32_16x16x32_f16(af[t][0], bf[u][0], acc[t][u], 0, 0, 0);
                acc[t][u] = __builtin_amdgcn_mfma_f32_16x16x32_f16(af[t][1], bf[u][1], acc[t][u], 0, 0, 0);
            }
    }

    const int rowbase = tm * 128 + wm + q * 4;
    const int colbase = tn * 128 + wn + cl;
#pragma unroll
    for (int t = 0; t < 4; t++)
#pragma unroll
        for (int r = 0; r < 4; r++) {
            size_t rb_ = (size_t)(rowbase + t * 16 + r) * ldc;
            size_t rb1 = (size_t)(rowbase + t * 16 + r) * 1024;
#pragma unroll
            for (int u = 0; u < 4; u++) {
                int gcol = colbase + u * 16;
                float v = acc[t][u][r];
                if (EPI == 0) {
                    if (gcol < 1024) ((f16*)C0)[rb1 + gcol] = (f16)v;
                    else             ((f16*)C1)[rb1 + gcol - 1024] = (f16)v;
                } else if (EPI == 1) {
                    if (gcol < N) ((float*)C0)[rb_ + gcol] = v;
                } else if (EPI == 2) {
                    if (gcol < N) atomicAdd((float*)C0 + rb_ + gcol, v);
                } else {
                    if (gcol < N) {
                        float sv = v + fbias[gcol];
                        sv = (sv > 15.f) ? sv : log1pf(__expf(sv));
                        ((f16*)C0)[rb_ + gcol] = (f16)sv;
                    }
                }
            }
        }
}

// ------- causal depthwise conv (K=4) + bias + silu, 4 rows per thread -------
__global__ __launch_bounds__(256) void conv_silu_kernel(const f16* __restrict__ x,
                                                        const float* __restrict__ cw,
                                                        const float* __restrict__ cb,
                                                        f16* __restrict__ xc) {
    const int rg = blockIdx.x;
    const int d = blockIdx.y * 256 + threadIdx.x;
    const int row0 = rg * 4;
    const int l0 = row0 & (LSEQ - 1);
    float w0 = cw[d * 4], w1 = cw[d * 4 + 1], w2 = cw[d * 4 + 2], w3 = cw[d * 4 + 3];
    float bias = cb[d];
    float v[7];
#pragma unroll
    for (int j = 0; j < 7; j++) {
        int ll = l0 - 3 + j;
        v[j] = (ll >= 0) ? (float)x[(size_t)(row0 - 3 + j) * 1024 + d] : 0.f;
    }
#pragma unroll
    for (int i = 0; i < 4; i++) {
        float acc = bias + w0 * v[i] + w1 * v[i + 1] + w2 * v[i + 2] + w3 * v[i + 3];
        xc[(size_t)(row0 + i) * 1024 + d] = (f16)(acc / (1.f + __expf(-acc)));
    }
}

// ---------------- selective scan: 64 chunks of 32, chunk-major state --------
// state layout: hF/Pb/h0 [c][b][d][n] -> offset ((c*4+b)*1024+d)*8+n
// Load batches double-buffered: group i+1's loads issue before group i's compute.
__global__ __launch_bounds__(256) void scan1_kernel(const f16* __restrict__ dt,
                                                    const f16* __restrict__ xc,
                                                    const float* __restrict__ dbl,
                                                    const float* __restrict__ A_log,
                                                    float* __restrict__ hF,
                                                    float* __restrict__ Pb) {
    const int d = blockIdx.x * 256 + threadIdx.x;
    const int c = blockIdx.y;
    const int b = blockIdx.z;
    __shared__ float sB[CHUNKL * NSTATE];   // 256 floats
    sB[threadIdx.x] = dbl[(size_t)(b * LSEQ + c * CHUNKL + (threadIdx.x >> 3)) * 80 + 64 + (threadIdx.x & 7)];
    __syncthreads();
    f32x4 al0 = *(const f32x4*)(A_log + d * 8);
    f32x4 al1 = *(const f32x4*)(A_log + d * 8 + 4);
    float Aa[NSTATE];
#pragma unroll
    for (int n = 0; n < 4; n++) { Aa[n] = -__expf(al0[n]); Aa[n + 4] = -__expf(al1[n]); }
    float h[NSTATE], P[NSTATE];
#pragma unroll
    for (int n = 0; n < NSTATE; n++) { h[n] = 0.f; P[n] = 1.f; }
    const f16* pdt = dt + (size_t)(b * LSEQ + c * CHUNKL) * 1024 + d;
    const f16* pxc = xc + (size_t)(b * LSEQ + c * CHUNKL) * 1024 + d;
    float vdt[2][8], vxc[2][8];
#pragma unroll
    for (int j = 0; j < 8; j++) {
        vdt[0][j] = (float)pdt[(size_t)j * 1024];
        vxc[0][j] = (float)pxc[(size_t)j * 1024];
    }
#pragma unroll
    for (int lb = 0; lb < CHUNKL; lb += 8) {
        const int cur = (lb >> 3) & 1;
        if (lb + 8 < CHUNKL) {
#pragma unroll
            for (int j = 0; j < 8; j++) {   // prefetch next group before compute
                vdt[cur ^ 1][j] = (float)pdt[(size_t)(lb + 8 + j) * 1024];
                vxc[cur ^ 1][j] = (float)pxc[(size_t)(lb + 8 + j) * 1024];
            }
        }
#pragma unroll
        for (int j = 0; j < 8; j++) {
            float dtx = vdt[cur][j] * vxc[cur][j];
#pragma unroll
            for (int n = 0; n < NSTATE; n++) {
                float e = __expf(Aa[n] * vdt[cur][j]);
                h[n] = e * h[n] + dtx * sB[(lb + j) * 8 + n];
                P[n] *= e;
            }
        }
    }
    size_t base = ((size_t)(c * 4 + b) * 1024 + d) * 8;
    f32x4 o;
    o[0]=h[0]; o[1]=h[1]; o[2]=h[2]; o[3]=h[3]; *(f32x4*)(hF + base) = o;
    o[0]=h[4]; o[1]=h[5]; o[2]=h[6]; o[3]=h[7]; *(f32x4*)(hF + base + 4) = o;
    o[0]=P[0]; o[1]=P[1]; o[2]=P[2]; o[3]=P[3]; *(f32x4*)(Pb + base) = o;
    o[0]=P[4]; o[1]=P[5]; o[2]=P[6]; o[3]=P[7]; *(f32x4*)(Pb + base + 4) = o;
}

// prefix combine over chunks: thread per (b,d,n), coalesced per c-step
__global__ __launch_bounds__(256) void combine_kernel(const float* __restrict__ hF,
                                                      const float* __restrict__ Pb,
                                                      float* __restrict__ h0) {
    int t = blockIdx.x * 256 + threadIdx.x;   // 32768 = 4b*1024d*8n
    int n = t & 7, dd = (t >> 3) & 1023, b = t >> 13;
    size_t off = (size_t)(b * 1024 + dd) * 8 + n;
    float h = 0.f;
#pragma unroll 8
    for (int c = 0; c < NCHUNK; c++) {
        size_t idx = (size_t)c * 32768 + off;
        h0[idx] = h;
        h = fmaf(Pb[idx], h, hF[idx]);
    }
}

__global__ __launch_bounds__(256) void scan2_kernel(const f16* __restrict__ dt,
                                                    const f16* __restrict__ xc,
                                                    const float* __restrict__ dbl,
                                                    const float* __restrict__ A_log,
                                                    const float* __restrict__ h0,
                                                    const f16* __restrict__ z,
                                                    const float* __restrict__ Dsk,
                                                    f16* __restrict__ yout) {
    const int d = blockIdx.x * 256 + threadIdx.x;
    const int c = blockIdx.y;
    const int b = blockIdx.z;
    __shared__ float sB[CHUNKL * NSTATE];
    __shared__ float sC[CHUNKL * NSTATE];
    {
        size_t rb = (size_t)(b * LSEQ + c * CHUNKL + (threadIdx.x >> 3)) * 80;
        sB[threadIdx.x] = dbl[rb + 64 + (threadIdx.x & 7)];
        sC[threadIdx.x] = dbl[rb + 72 + (threadIdx.x & 7)];
    }
    __syncthreads();
    f32x4 al0 = *(const f32x4*)(A_log + d * 8);
    f32x4 al1 = *(const f32x4*)(A_log + d * 8 + 4);
    float Aa[NSTATE];
#pragma unroll
    for (int n = 0; n < 4; n++) { Aa[n] = -__expf(al0[n]); Aa[n + 4] = -__expf(al1[n]); }
    float h[NSTATE];
    {
        size_t base = ((size_t)(c * 4 + b) * 1024 + d) * 8;
        f32x4 h0a = *(const f32x4*)(h0 + base);
        f32x4 h0b = *(const f32x4*)(h0 + base + 4);
#pragma unroll
        for (int n = 0; n < 4; n++) { h[n] = h0a[n]; h[n + 4] = h0b[n]; }
    }
    const float dval = Dsk[d];
    const size_t rowoff = (size_t)(b * LSEQ + c * CHUNKL) * 1024 + d;
    const f16* pdt = dt + rowoff;
    const f16* pxc = xc + rowoff;
    const f16* pz  = z  + rowoff;
    f16* py = yout + rowoff;
    float vdt[2][8], vxc[2][8], vz[2][8];
#pragma unroll
    for (int j = 0; j < 8; j++) {
        vdt[0][j] = (float)pdt[(size_t)j * 1024];
        vxc[0][j] = (float)pxc[(size_t)j * 1024];
        vz[0][j]  = (float)pz[(size_t)j * 1024];
    }
#pragma unroll
    for (int lb = 0; lb < CHUNKL; lb += 8) {
        const int cur = (lb >> 3) & 1;
        if (lb + 8 < CHUNKL) {
#pragma unroll
            for (int j = 0; j < 8; j++) {   // prefetch next group before compute
                vdt[cur ^ 1][j] = (float)pdt[(size_t)(lb + 8 + j) * 1024];
                vxc[cur ^ 1][j] = (float)pxc[(size_t)(lb + 8 + j) * 1024];
                vz[cur ^ 1][j]  = (float)pz[(size_t)(lb + 8 + j) * 1024];
            }
        }
#pragma unroll
        for (int j = 0; j < 8; j++) {
            float dtx = vdt[cur][j] * vxc[cur][j];
            float y = 0.f;
#pragma unroll
            for (int n = 0; n < NSTATE; n++) {
                float e = __expf(Aa[n] * vdt[cur][j]);
                h[n] = e * h[n] + dtx * sB[(lb + j) * 8 + n];
                y += h[n] * sC[(lb + j) * 8 + n];
            }
            y += dval * vxc[cur][j];
            y *= vz[cur][j] / (1.f + __expf(-vz[cur][j]));
            py[(size_t)(lb + j) * 1024] = (f16)y;
        }
    }
}

extern "C" void kernel_launch(void* const* d_in, const int* in_sizes, int n_in,
                              void* d_out, int out_size, void* d_ws, size_t ws_size,
                              hipStream_t stream) {
    (void)in_sizes; (void)n_in;
    const float* hidden    = (const float*)d_in[0];
    const float* norm_w    = (const float*)d_in[1];
    const float* in_proj_w = (const float*)d_in[2];
    const float* conv_w    = (const float*)d_in[3];
    const float* conv_b    = (const float*)d_in[4];
    const float* x_proj_w  = (const float*)d_in[5];
    const float* dt_proj_w = (const float*)d_in[6];
    const float* dt_proj_b = (const float*)d_in[7];
    const float* A_log     = (const float*)d_in[8];
    const float* D_skip    = (const float*)d_in[9];
    const float* out_proj_w= (const float*)d_in[10];
    float* out = (float*)d_out;

    if (ws_size < WS_NEED) {
        sentinel_kernel<<<dim3((out_size + 255) / 256), 256, 0, stream>>>(out, out_size);
        return;
    }

    char* ws = (char*)d_ws;
    f16*   xn_h  = (f16*)(ws);                         // [0,16) -> y_h later
    f16*   xbuf_h= (f16*)(ws + (16ull << 20));         // [16,32)
    f16*   zbuf_h= (f16*)(ws + (32ull << 20));         // [32,48)
    f16*   xc_h  = (f16*)(ws + (48ull << 20));         // [48,64)
    f16*   wih   = (f16*)(ws + (64ull << 20));         // [64,68)
    f16*   woh   = (f16*)(ws + (68ull << 20));         // [68,70)
    f16*   wxh   = (f16*)(ws + (70ull << 20));         // 160 KB
    f16*   wdh   = (f16*)(ws + (70ull << 20) + (512ull << 10));  // 128 KB
    float* dbl_f = (float*)(ws + (71ull << 20));       // 2.5 MB
    f16*   dth   = (f16*)(ws + (75ull << 20));         // [75,91)
    float* hF    = (float*)(ws + (91ull << 20));       // 8 MB
    float* Pb    = (float*)(ws + (99ull << 20));       // 8 MB
    float* h0    = (float*)(ws + (107ull << 20));      // 8 MB
    f16*   y_h   = xn_h;

    prep_kernel<<<dim3(WCVT_BLK + ZERO_BLK + NROWS), 256, 0, stream>>>(
        in_proj_w, x_proj_w, dt_proj_w, out_proj_w, wih, wxh, wdh, woh,
        dbl_f, hidden, norm_w, xn_h);
    gemm_f16<0, 0><<<dim3(64, 16), 256, 0, stream>>>(xn_h, 1024, wih, 1024,
                                                     xbuf_h, zbuf_h, 1024, 2048, 1024, nullptr);
    conv_silu_kernel<<<dim3(NROWS / 4, 4), 256, 0, stream>>>(xbuf_h, conv_w, conv_b, xc_h);
    gemm_f16<2, 0><<<dim3(64, 1, 4), 256, 0, stream>>>(xc_h, 1024, wxh, 1024,
                                                       dbl_f, nullptr, 80, 80, 256, nullptr);
    gemm_f16<3, 1><<<dim3(64, 8), 256, 0, stream>>>(dbl_f, 80, wdh, 64,
                                                    dth, nullptr, 1024, 1024, 64, dt_proj_b);
    scan1_kernel<<<dim3(4, NCHUNK, 4), 256, 0, stream>>>(dth, xc_h, dbl_f, A_log, hF, Pb);
    combine_kernel<<<dim3(128), 256, 0, stream>>>(hF, Pb, h0);
    scan2_kernel<<<dim3(4, NCHUNK, 4), 256, 0, stream>>>(dth, xc_h, dbl_f, A_log, h0,
                                                         zbuf_h, D_skip, y_h);
    gemm_f16<1, 0><<<dim3(64, 8), 256, 0, stream>>>(y_h, 1024, woh, 1024,
                                                    out, nullptr, 1024, 1024, 1024, nullptr);
}